// Round 2
// baseline (201.329 us; speedup 1.0000x reference)
//
#include <hip/hip_runtime.h>
#include <math.h>

// MinkowskiInstanceNorm: segment instance-norm, N rows x C=32 channels, S segments.
// ws layout (floats): SUM[64*32] @0, SUMSQ @2048, SCALE @4096, SHIFT @6144.

#define WS_SUM   0
#define WS_SUMSQ 2048
#define WS_SCALE 4096
#define WS_SHIFT 6144

__global__ void zero_ws_kernel(float* __restrict__ ws) {
    int t = blockIdx.x * blockDim.x + threadIdx.x;
    if (t < 4096) ws[t] = 0.0f;   // zero SUM + SUMSQ regions
}

// Block b handles contiguous rows [b*chunk, min(N,(b+1)*chunk)).
// thread t: cg = t&7 (which float4 of the row), rl = t>>3 (row offset mod 32).
__global__ __launch_bounds__(256) void reduce_kernel(
        const float4* __restrict__ feats4, const int* __restrict__ seg,
        float* __restrict__ ws, int N, int chunk) {
    __shared__ float4 s_sum[256];
    __shared__ float4 s_sq[256];
    float* sum_g   = ws + WS_SUM;
    float* sumsq_g = ws + WS_SUMSQ;

    int t  = threadIdx.x;
    int cg = t & 7;
    int rl = t >> 3;
    int bstart = blockIdx.x * chunk;
    if (bstart >= N) return;                  // uniform across block
    int bend = min(N, bstart + chunk);

    int seg_first = seg[bstart];
    int seg_last  = seg[bend - 1];

    for (int s = seg_first; s <= seg_last; ++s) {
        float4 acc  = make_float4(0.f, 0.f, 0.f, 0.f);
        float4 accq = make_float4(0.f, 0.f, 0.f, 0.f);
        for (int r = bstart + rl; r < bend; r += 32) {
            if (seg[r] == s) {
                float4 v = feats4[r * 8 + cg];
                acc.x  += v.x;       acc.y  += v.y;
                acc.z  += v.z;       acc.w  += v.w;
                accq.x += v.x * v.x; accq.y += v.y * v.y;
                accq.z += v.z * v.z; accq.w += v.w * v.w;
            }
        }
        s_sum[t] = acc;
        s_sq[t]  = accq;
        __syncthreads();
        // reduce across rl (strides that preserve cg: multiples of 8)
        for (int off = 128; off >= 8; off >>= 1) {
            if (t < off) {
                float4 a = s_sum[t + off], b = s_sq[t + off];
                s_sum[t].x += a.x; s_sum[t].y += a.y;
                s_sum[t].z += a.z; s_sum[t].w += a.w;
                s_sq[t].x  += b.x; s_sq[t].y  += b.y;
                s_sq[t].z  += b.z; s_sq[t].w  += b.w;
            }
            __syncthreads();
        }
        if (t < 8) {   // thread t holds totals for channels [t*4, t*4+4)
            float4 a = s_sum[t], b = s_sq[t];
            int base = s * 32 + t * 4;
            atomicAdd(&sum_g[base + 0], a.x);
            atomicAdd(&sum_g[base + 1], a.y);
            atomicAdd(&sum_g[base + 2], a.z);
            atomicAdd(&sum_g[base + 3], a.w);
            atomicAdd(&sumsq_g[base + 0], b.x);
            atomicAdd(&sumsq_g[base + 1], b.y);
            atomicAdd(&sumsq_g[base + 2], b.z);
            atomicAdd(&sumsq_g[base + 3], b.w);
        }
        __syncthreads();
    }
}

__device__ inline int lower_bound(const int* __restrict__ a, int n, int key) {
    int lo = 0, hi = n;
    while (lo < hi) {
        int mid = (lo + hi) >> 1;
        if (a[mid] < key) lo = mid + 1; else hi = mid;
    }
    return lo;
}

__global__ void stats_kernel(const int* __restrict__ seg,
                             const float* __restrict__ w,
                             const float* __restrict__ b,
                             const int* __restrict__ nsp,
                             float* __restrict__ ws, int N) {
    __shared__ int s_cnt[64];
    const float* sum_g   = ws + WS_SUM;
    const float* sumsq_g = ws + WS_SUMSQ;
    float* scale_g = ws + WS_SCALE;
    float* shift_g = ws + WS_SHIFT;

    int t  = threadIdx.x;
    int ns = *nsp;
    for (int s = t; s < ns; s += blockDim.x)
        s_cnt[s] = lower_bound(seg, N, s + 1) - lower_bound(seg, N, s);
    __syncthreads();

    for (int i = t; i < ns * 32; i += blockDim.x) {
        int s = i >> 5, c = i & 31;
        float cnt  = fmaxf((float)s_cnt[s], 1.0f);
        float mean = sum_g[i] / cnt;
        float var  = fmaxf(sumsq_g[i] / cnt - mean * mean, 0.0f);
        float inv  = rsqrtf(var + 1e-8f);
        float sc   = inv * w[c];
        scale_g[i] = sc;
        shift_g[i] = b[c] - mean * sc;
    }
}

__global__ __launch_bounds__(256) void apply_kernel(
        const float4* __restrict__ feats4, const int* __restrict__ seg,
        const float* __restrict__ ws, float4* __restrict__ out4, int total4) {
    const float4* scale4 = (const float4*)(ws + WS_SCALE);
    const float4* shift4 = (const float4*)(ws + WS_SHIFT);
    int stride = gridDim.x * blockDim.x;
    for (int i = blockIdx.x * blockDim.x + threadIdx.x; i < total4; i += stride) {
        int row = i >> 3, cg = i & 7;
        int s = seg[row];
        float4 v  = feats4[i];
        float4 sc = scale4[s * 8 + cg];
        float4 sh = shift4[s * 8 + cg];
        float4 o;
        o.x = fmaf(v.x, sc.x, sh.x);
        o.y = fmaf(v.y, sc.y, sh.y);
        o.z = fmaf(v.z, sc.z, sh.z);
        o.w = fmaf(v.w, sc.w, sh.w);
        out4[i] = o;
    }
}

extern "C" void kernel_launch(void* const* d_in, const int* in_sizes, int n_in,
                              void* d_out, int out_size, void* d_ws, size_t ws_size,
                              hipStream_t stream) {
    const float* feats = (const float*)d_in[0];
    const int*   seg   = (const int*)d_in[1];
    const float* w     = (const float*)d_in[2];
    const float* b     = (const float*)d_in[3];
    const int*   nsp   = (const int*)d_in[4];
    float* out = (float*)d_out;
    float* ws  = (float*)d_ws;

    int N = in_sizes[1];               // number of rows (seg_ids length)
    int total4 = N * 8;                // N * 32 channels / 4 per float4

    const int NB = 2048;
    int chunk = (N + NB - 1) / NB;

    hipLaunchKernelGGL(zero_ws_kernel, dim3(16), dim3(256), 0, stream, ws);
    hipLaunchKernelGGL(reduce_kernel, dim3(NB), dim3(256), 0, stream,
                       (const float4*)feats, seg, ws, N, chunk);
    hipLaunchKernelGGL(stats_kernel, dim3(1), dim3(256), 0, stream,
                       seg, w, b, nsp, ws, N);
    hipLaunchKernelGGL(apply_kernel, dim3(4096), dim3(256), 0, stream,
                       (const float4*)feats, seg, ws, (float4*)out, total4);
}